// Round 6
// baseline (79.472 us; speedup 1.0000x reference)
//
#include <hip/hip_runtime.h>

// FlatPoolIco: icosahedral 7-neighbor hex pooling with chart stitching.
// Input  x: (B=64, R=6, C=5, H=128, W=256) f32
// Output  : (B=64, R=6, C=5, 64, 128) f32
//
// out(h,w) = mean of 7 taps:
//   row 2h-1: cols {2w-1, 2w}          (padded row 0 when h==0)
//   row 2h  : cols {2w-1, 2w, 2w+1}
//   row 2h+1: cols {2w, 2w+1}
// Boundary stitches (only padded row 0 / col 0 reachable):
//   padded(0,pw): pw==0        -> x[b,0,0,0,0]
//                 pw in [1,128]  -> x[rot,      (c+4)%5, 127, 127+pw]
//                 pw in [129,256]-> x[(rot+1)%6,(c+4)%5, 256-pw, 255]
//   padded(ph,0): ph in [1,128]  -> x[(rot+5)%6,(c+4)%5, 127, 128-ph]
// Input vertex mask is redundant; output mask zeroes (63,0),(0,127)/slab.
//
// v4: 16 outputs/thread (8 lanes per output row, 32 input cols/thread).
//     Mid+bot rows loaded and accumulated first (16 f4 loads in flight),
//     then top row — keeps peak VGPR ~90 for 5 waves/SIMD while doubling
//     per-thread MLP vs v2. Left edges via __shfl_up, NT stores.

#define WW 256

typedef float vfloat4 __attribute__((ext_vector_type(4)));

__device__ __forceinline__ void load32(const float* p, float* d) {
    #pragma unroll
    for (int q = 0; q < 8; ++q) {
        vfloat4 v = *(const vfloat4*)(p + q * 4);
        d[q*4+0] = v.x; d[q*4+1] = v.y; d[q*4+2] = v.z; d[q*4+3] = v.w;
    }
}

__global__ __launch_bounds__(256) void flat_pool_ico(const float* __restrict__ x,
                                                     float* __restrict__ out) {
    int t = blockIdx.x * 256 + threadIdx.x;
    int lane = t & 7;            // 8 threads per output row
    int rowid = t >> 3;
    int h = rowid & 63;
    int tmp = rowid >> 6;
    int c = tmp % 5; tmp /= 5;
    int rot = tmp % 6;
    int b = tmp / 6;
    int w0 = lane << 4;          // output col start: 0,16,...,112
    int cm = w0 << 1;            // input col base:   32*lane

    long slab = (long)((b * 6 + rot) * 5 + c);
    const float* xs   = x + (slab << 15);     // own slab (32768 floats)
    const float* rowm = xs + (h << 9);        // input row 2h
    const float* rowb = rowm + WW;            // input row 2h+1

    int cprev = (c + 4) % 5;
    const float* xn3 = x + ((long)((b * 6 + (rot + 5) % 6) * 5 + cprev) << 15) + 127 * WW;

    const float inv7 = 1.0f / 7.0f;
    float o[16];

    // ---- phase 1: mid row (cols cm-1..cm+32) + bot row (cols cm..cm+31) ----
    {
        float Mv[32], Bv[32];
        load32(rowm + cm, Mv);               // M cols cm..cm+31
        load32(rowb + cm, Bv);               // B cols cm..cm+31
        float midL = __shfl_up(Mv[31], 1);   // prev lane's col cm-1
        if (lane == 0) midL = xn3[127 - (h << 1)];   // padded(2h+1, 0)
        // M[j] (col cm+j-1): j=0 -> midL, j>=1 -> Mv[j-1]
        #pragma unroll
        for (int k = 0; k < 16; ++k) {
            float m0 = (k == 0) ? midL : Mv[2*k - 1];
            float s = m0 + Mv[2*k] + Mv[2*k+1]
                    + Bv[2*k] + Bv[2*k+1];
            o[k] = s;
        }
    }

    // ---- phase 2: top row ----
    if (h == 0) {
        // padded row 0: taps padded(0, cm+2k) and padded(0, cm+2k+1)
        const float* xn1 = x + ((long)((b * 6 + rot) * 5 + cprev) << 15) + 127 * WW + 127;
        const float* xn2 = x + ((long)((b * 6 + (rot + 1) % 6) * 5 + cprev) << 15) + 255;
        #pragma unroll
        for (int i = 0; i < 32; ++i) {
            int pw = cm + i;
            float v;
            if (pw == 0)        v = x[(long)b * 983040];   // corner -> flat idx 0
            else if (pw <= 128) v = xn1[pw];               // nbr chart row 127
            else                v = xn2[(256 - pw) << 8];  // nbr rot col 255
            o[i >> 1] += v;
        }
    } else {
        float Tv[32];
        load32(rowm - WW + cm, Tv);          // row 2h-1 cols cm..cm+31
        float topL = __shfl_up(Tv[31], 1);   // prev lane's col cm-1
        if (lane == 0) topL = xn3[128 - (h << 1)];   // padded(2h, 0)
        // T[j] (col cm+j-1): j=0 -> topL, j>=1 -> Tv[j-1]
        #pragma unroll
        for (int k = 0; k < 16; ++k) {
            float t0 = (k == 0) ? topL : Tv[2*k - 1];
            o[k] += t0 + Tv[2*k];
        }
    }

    #pragma unroll
    for (int k = 0; k < 16; ++k) o[k] *= inv7;

    // output vertex mask: (63,0) and (0,127)
    if (h == 63 && lane == 0) o[0]  = 0.0f;
    if (h == 0  && lane == 7) o[15] = 0.0f;

    float* op = out + (slab << 13) + (h << 7) + w0;
    #pragma unroll
    for (int q = 0; q < 4; ++q) {
        vfloat4 s = { o[q*4], o[q*4+1], o[q*4+2], o[q*4+3] };
        __builtin_nontemporal_store(s, (vfloat4*)(op + q * 4));
    }
}

extern "C" void kernel_launch(void* const* d_in, const int* in_sizes, int n_in,
                              void* d_out, int out_size, void* d_ws, size_t ws_size,
                              hipStream_t stream) {
    const float* x = (const float*)d_in[0];
    float* out = (float*)d_out;
    // threads = 64*6*5*64*8 = 983,040 ; 256/block -> 3840 blocks
    flat_pool_ico<<<3840, 256, 0, stream>>>(x, out);
}

// Round 7
// 76.638 us; speedup vs baseline: 1.0370x; 1.0370x over previous
//
#include <hip/hip_runtime.h>

// FlatPoolIco: icosahedral 7-neighbor hex pooling with chart stitching.
// Input  x: (B=64, R=6, C=5, H=128, W=256) f32
// Output  : (B=64, R=6, C=5, 64, 128) f32
//
// out(h,w) = mean of 7 taps:
//   row 2h-1: cols {2w-1, 2w}          (padded row 0 when h==0)
//   row 2h  : cols {2w-1, 2w, 2w+1}
//   row 2h+1: cols {2w, 2w+1}
// Boundary stitches (only padded row 0 / col 0 reachable):
//   padded(0,pw): pw==0        -> x[b,0,0,0,0]
//                 pw in [1,128]  -> x[rot,      (c+4)%5, 127, 127+pw]
//                 pw in [129,256]-> x[(rot+1)%6,(c+4)%5, 256-pw, 255]
//   padded(ph,0): ph in [1,128]  -> x[(rot+5)%6,(c+4)%5, 127, 128-ph]
// Input vertex mask is redundant; output mask zeroes (63,0),(0,127)/slab.
//
// v5: paired output rows per thread (h0 even, h1=h0+1) sharing input row
//     2h0+1 -> 5 row-loads per 16 outputs instead of 6 (VMEM instrs -17%).
//     3-phase accumulate-early schedule keeps peak liveness <= v2's
//     (~48 floats), preserving the v2 occupancy that v4 lost.
//     16 lanes/row, 8 cols/lane, __shfl_up edges, NT stores.

#define WW 256

typedef float vfloat4 __attribute__((ext_vector_type(4)));

__device__ __forceinline__ void load16(const float* p, float* d) {
    #pragma unroll
    for (int q = 0; q < 4; ++q) {
        vfloat4 v = *(const vfloat4*)(p + q * 4);
        d[q*4+0] = v.x; d[q*4+1] = v.y; d[q*4+2] = v.z; d[q*4+3] = v.w;
    }
}

__global__ __launch_bounds__(256) void flat_pool_ico(const float* __restrict__ x,
                                                     float* __restrict__ out) {
    int t = blockIdx.x * 256 + threadIdx.x;
    int lane = t & 15;           // 16 lanes per output row
    int pid  = t >> 4;           // global row-pair id
    int pr   = pid & 31;         // pair within slab (rows h0=2pr, h1=2pr+1)
    int slab = pid >> 5;         // 0..1919
    int h0   = pr << 1;
    int c    = slab % 5;
    int rc   = slab / 5;         // b*6 + rot
    int rot  = rc % 6;
    int b    = rc / 6;
    int w0   = lane << 3;        // output col start
    int cm   = w0 << 1;          // input col base (16 per lane)

    const float* xs = x + ((long)slab << 15);
    const float* r1p = xs + (h0 << 9);        // input row 2h0
    int cprev = (c + 4) % 5;
    const float* xn3 = x + ((long)((b * 6 + (rot + 5) % 6) * 5 + cprev) << 15) + 127 * WW;

    float o1[8], o2[8];

    // ---- phase A: r1 = row 2h0, r2 = row 2h0+1 ----
    {
        float R1[16], R2[16];
        load16(r1p + cm, R1);
        load16(r1p + WW + cm, R2);
        float r1L = __shfl_up(R1[15], 1);
        if (lane == 0) r1L = xn3[127 - (h0 << 1)];       // padded(2h0+1, 0)
        float r2L = __shfl_up(R2[15], 1);
        if (lane == 0) r2L = xn3[126 - (h0 << 1)];       // padded(2h0+2, 0)
        #pragma unroll
        for (int k = 0; k < 8; ++k) {
            int j = 2 * k;
            float m0 = k ? R1[j - 1] : r1L;
            o1[k] = m0 + R1[j] + R1[j + 1] + R2[j] + R2[j + 1];
            float t0 = k ? R2[j - 1] : r2L;
            o2[k] = t0 + R2[j];
        }
    }

    const float inv7 = 1.0f / 7.0f;
    float* op = out + ((long)slab << 13) + (h0 << 7) + w0;

    // ---- phase B: r0 = row 2h0-1 (padded row 0 when h0==0) ----
    if (h0 == 0) {
        const float* xn1 = x + ((long)(rc * 5 + cprev) << 15) + 127 * WW + 127;
        const float* xn2 = x + ((long)((b * 6 + (rot + 1) % 6) * 5 + cprev) << 15) + 255;
        #pragma unroll
        for (int i = 0; i < 16; ++i) {
            int pw = cm + i;
            float v;
            if (pw == 0)        v = x[(long)b * 983040];   // corner -> flat idx 0
            else if (pw <= 128) v = xn1[pw];               // nbr chart row 127
            else                v = xn2[(256 - pw) << 8];  // nbr rot col 255
            o1[i >> 1] += v;
        }
    } else {
        float R0[16];
        load16(r1p - WW + cm, R0);
        float r0L = __shfl_up(R0[15], 1);
        if (lane == 0) r0L = xn3[128 - (h0 << 1)];       // padded(2h0, 0)
        #pragma unroll
        for (int k = 0; k < 8; ++k) {
            int j = 2 * k;
            o1[k] += (k ? R0[j - 1] : r0L) + R0[j];
        }
    }

    #pragma unroll
    for (int k = 0; k < 8; ++k) o1[k] *= inv7;
    if (h0 == 0 && lane == 15) o1[7] = 0.0f;             // vertex (0,127)
    {
        vfloat4 s0 = { o1[0], o1[1], o1[2], o1[3] };
        vfloat4 s1 = { o1[4], o1[5], o1[6], o1[7] };
        __builtin_nontemporal_store(s0, (vfloat4*)op);
        __builtin_nontemporal_store(s1, (vfloat4*)(op + 4));
    }

    // ---- phase C: r3 = row 2h0+2, r4 = row 2h0+3 ----
    {
        float R3[16], R4[16];
        load16(r1p + 2 * WW + cm, R3);
        load16(r1p + 3 * WW + cm, R4);
        float r3L = __shfl_up(R3[15], 1);
        if (lane == 0) r3L = xn3[125 - (h0 << 1)];       // padded(2h0+3, 0)
        #pragma unroll
        for (int k = 0; k < 8; ++k) {
            int j = 2 * k;
            o2[k] += (k ? R3[j - 1] : r3L) + R3[j] + R3[j + 1]
                   + R4[j] + R4[j + 1];
            o2[k] *= inv7;
        }
    }
    if (h0 == 62 && lane == 0) o2[0] = 0.0f;             // vertex (63,0)
    {
        vfloat4 s0 = { o2[0], o2[1], o2[2], o2[3] };
        vfloat4 s1 = { o2[4], o2[5], o2[6], o2[7] };
        __builtin_nontemporal_store(s0, (vfloat4*)(op + 128));
        __builtin_nontemporal_store(s1, (vfloat4*)(op + 132));
    }
}

extern "C" void kernel_launch(void* const* d_in, const int* in_sizes, int n_in,
                              void* d_out, int out_size, void* d_ws, size_t ws_size,
                              hipStream_t stream) {
    const float* x = (const float*)d_in[0];
    float* out = (float*)d_out;
    // threads = 1920 slabs * 32 pairs * 16 lanes = 983,040 ; 3840 blocks
    flat_pool_ico<<<3840, 256, 0, stream>>>(x, out);
}

// Round 8
// 58.787 us; speedup vs baseline: 1.3519x; 1.3037x over previous
//
#include <hip/hip_runtime.h>

// FlatPoolIco: icosahedral 7-neighbor hex pooling with chart stitching.
// Input  x: (B=64, R=6, C=5, H=128, W=256) f32
// Output  : (B=64, R=6, C=5, 64, 128) f32
//
// out(h,w) = mean of 7 taps:
//   row 2h-1: cols {2w-1, 2w}          (padded row 0 when h==0)
//   row 2h  : cols {2w-1, 2w, 2w+1}
//   row 2h+1: cols {2w, 2w+1}
// Boundary stitches (only padded row 0 / col 0 reachable):
//   padded(0,pw): pw==0        -> x[b,0,0,0,0]
//                 pw in [1,128]  -> x[rot,      (c+4)%5, 127, 127+pw]
//                 pw in [129,256]-> x[(rot+1)%6,(c+4)%5, 256-pw, 255]
//   padded(ph,0): ph in [1,128]  -> x[(rot+5)%6,(c+4)%5, 127, 128-ph]
// Input vertex mask is redundant; output mask zeroes (63,0),(0,127)/slab.
//
// FINAL (v2): 8 outputs/thread, 16 lanes per output row, __shfl_up edges,
// NT stores. 2M threads is the latency-hiding sweet spot: v3 (rolling
// strip), v4 (16 outputs/thread), v5 (row-pair sharing) all halved thread
// count and regressed to 69-79us; v2 holds 58.7us = ~5.4 TB/s raw, ~85-90%
// of the 6.3 TB/s mixed-stream ceiling (byte floor ~50us + launch/ramp).

#define WW 256

typedef float vfloat4 __attribute__((ext_vector_type(4)));

__global__ __launch_bounds__(256) void flat_pool_ico(const float* __restrict__ x,
                                                     float* __restrict__ out) {
    int t = blockIdx.x * 256 + threadIdx.x;
    int lane = t & 15;           // 16 threads per output row
    int rowid = t >> 4;
    int h = rowid & 63;
    int tmp = rowid >> 6;
    int c = tmp % 5; tmp /= 5;
    int rot = tmp % 6;
    int b = tmp / 6;
    int w0 = lane << 3;          // output col start: 0..120
    int cm = w0 << 1;            // input col base:   16*lane

    long slab = (long)((b * 6 + rot) * 5 + c);
    const float* xs   = x + (slab << 15);     // own slab (32768 floats)
    const float* rowm = xs + (h << 9);        // input row 2h
    const float* rowb = rowm + WW;            // input row 2h+1

    // M[j] = row 2h   col cm+j-1   (j=0..16)
    // T[j] = row 2h-1 col cm+j-1,  or padded(0, cm+j) when h==0  (j=0..15)
    // B[j] = row 2h+1 col cm+j     (j=0..15)
    float M[17], T[16], B[16];

    {
        vfloat4 a0 = *(const vfloat4*)(rowm + cm);
        vfloat4 a1 = *(const vfloat4*)(rowm + cm + 4);
        vfloat4 a2 = *(const vfloat4*)(rowm + cm + 8);
        vfloat4 a3 = *(const vfloat4*)(rowm + cm + 12);
        M[1]=a0.x;  M[2]=a0.y;  M[3]=a0.z;  M[4]=a0.w;
        M[5]=a1.x;  M[6]=a1.y;  M[7]=a1.z;  M[8]=a1.w;
        M[9]=a2.x;  M[10]=a2.y; M[11]=a2.z; M[12]=a2.w;
        M[13]=a3.x; M[14]=a3.y; M[15]=a3.z; M[16]=a3.w;
        vfloat4 c0 = *(const vfloat4*)(rowb + cm);
        vfloat4 c1 = *(const vfloat4*)(rowb + cm + 4);
        vfloat4 c2 = *(const vfloat4*)(rowb + cm + 8);
        vfloat4 c3 = *(const vfloat4*)(rowb + cm + 12);
        B[0]=c0.x;  B[1]=c0.y;  B[2]=c0.z;  B[3]=c0.w;
        B[4]=c1.x;  B[5]=c1.y;  B[6]=c1.z;  B[7]=c1.w;
        B[8]=c2.x;  B[9]=c2.y;  B[10]=c2.z; B[11]=c2.w;
        B[12]=c3.x; B[13]=c3.y; B[14]=c3.z; B[15]=c3.w;
    }

    int cprev = (c + 4) % 5;
    const float* xn3 = x + ((long)((b * 6 + (rot + 5) % 6) * 5 + cprev) << 15) + 127 * WW;

    // left edge of mid row: col cm-1 (prev lane's M[16]); lane 0 stitched
    {
        float midL = __shfl_up(M[16], 1);
        if (lane == 0) midL = xn3[127 - (h << 1)];   // padded(1+2h, 0)
        M[0] = midL;
    }

    if (h == 0) {
        // padded row 0: T[i] = padded(0, cm+i)
        const float* xn1 = x + ((long)((b * 6 + rot) * 5 + cprev) << 15) + 127 * WW + 127;
        const float* xn2 = x + ((long)((b * 6 + (rot + 1) % 6) * 5 + cprev) << 15) + 255;
        #pragma unroll
        for (int i = 0; i < 16; ++i) {
            int pw = cm + i;
            float v;
            if (pw == 0)        v = x[(long)b * 983040];   // corner -> flat idx 0
            else if (pw <= 128) v = xn1[pw];               // nbr chart row 127
            else                v = xn2[(256 - pw) << 8];  // nbr rot col 255
            T[i] = v;
        }
    } else {
        const float* rowt = rowm - WW;        // input row 2h-1
        vfloat4 t0 = *(const vfloat4*)(rowt + cm);
        vfloat4 t1 = *(const vfloat4*)(rowt + cm + 4);
        vfloat4 t2 = *(const vfloat4*)(rowt + cm + 8);
        vfloat4 t3 = *(const vfloat4*)(rowt + cm + 12);
        T[1]=t0.x;  T[2]=t0.y;  T[3]=t0.z;  T[4]=t0.w;
        T[5]=t1.x;  T[6]=t1.y;  T[7]=t1.z;  T[8]=t1.w;
        T[9]=t2.x;  T[10]=t2.y; T[11]=t2.z; T[12]=t2.w;
        T[13]=t3.x; T[14]=t3.y; T[15]=t3.z;
        float topL = __shfl_up(t3.w, 1);      // prev lane's col cm-1
        if (lane == 0) topL = xn3[128 - (h << 1)];   // padded(2h, 0)
        T[0] = topL;
    }

    const float inv7 = 1.0f / 7.0f;
    float o[8];
    #pragma unroll
    for (int k = 0; k < 8; ++k) {
        float s = M[2*k] + M[2*k+1] + M[2*k+2]
                + T[2*k] + T[2*k+1]
                + B[2*k] + B[2*k+1];
        o[k] = s * inv7;
    }

    // output vertex mask: (63,0) and (0,127)
    if (h == 63 && lane == 0)  o[0] = 0.0f;
    if (h == 0  && lane == 15) o[7] = 0.0f;

    float* op = out + (slab << 13) + (h << 7) + w0;
    vfloat4 s0 = { o[0], o[1], o[2], o[3] };
    vfloat4 s1 = { o[4], o[5], o[6], o[7] };
    __builtin_nontemporal_store(s0, (vfloat4*)op);
    __builtin_nontemporal_store(s1, (vfloat4*)(op + 4));
}

extern "C" void kernel_launch(void* const* d_in, const int* in_sizes, int n_in,
                              void* d_out, int out_size, void* d_ws, size_t ws_size,
                              hipStream_t stream) {
    const float* x = (const float*)d_in[0];
    float* out = (float*)d_out;
    // threads = 64*6*5*64*16 = 1,966,080 ; 256/block -> 7680 blocks
    flat_pool_ico<<<7680, 256, 0, stream>>>(x, out);
}